// Round 6
// baseline (1452.264 us; speedup 1.0000x reference)
//
#include <hip/hip_runtime.h>
#include <hip/hip_bf16.h>

using bf16 = __hip_bfloat16;
typedef __attribute__((ext_vector_type(8))) short short8;
typedef __attribute__((ext_vector_type(4))) short short4v;
typedef __attribute__((ext_vector_type(4))) float f32x4;

__device__ __forceinline__ float bfbits2f(unsigned short h) {
    unsigned v = (unsigned)h << 16;
    return __uint_as_float(v);
}

__device__ __forceinline__ void gload16(const void* g, void* l) {
    __builtin_amdgcn_global_load_lds(
        (const __attribute__((address_space(1))) unsigned int*)g,
        (__attribute__((address_space(3))) unsigned int*)l, 16, 0, 0);
}

// tanh-form GELU: ~8 VALU; |diff vs exact erf-GELU| <= ~3e-3
__device__ __forceinline__ float gelu_fast(float x) {
    float x2 = x * x;
    float u = x * __builtin_fmaf(0.07135481f, x2, 1.59576912f);
    float e = __expf(u);
    return x - x * __builtin_amdgcn_rcpf(e + 1.0f);
}

// ---- block reduce over 3 waves (192 threads) ----
__device__ __forceinline__ float blk_sum3(float v, float* red) {
#pragma unroll
    for (int o = 32; o > 0; o >>= 1) v += __shfl_down(v, o, 64);
    int wv = threadIdx.x >> 6;
    __syncthreads();
    if ((threadIdx.x & 63) == 0) red[wv] = v;
    __syncthreads();
    return red[0] + red[1] + red[2];
}

// ---- LayerNorm over D=768, one block per row, f32 in -> bf16 out ----
__global__ __launch_bounds__(192) void ln_f32(const float* __restrict__ x,
                                              const float* __restrict__ g,
                                              const float* __restrict__ b,
                                              bf16* __restrict__ y) {
    __shared__ float red[3];
    size_t base = (size_t)blockIdx.x * 768;
    int t = threadIdx.x;
    float4 v = *(const float4*)&x[base + t * 4];
    float s = blk_sum3(v.x + v.y + v.z + v.w, red);
    float mean = s * (1.0f / 768.0f);
    float d0 = v.x - mean, d1 = v.y - mean, d2 = v.z - mean, d3 = v.w - mean;
    float sq = blk_sum3(d0 * d0 + d1 * d1 + d2 * d2 + d3 * d3, red);
    float rstd = rsqrtf(sq * (1.0f / 768.0f) + 1e-6f);
    float4 gv = *(const float4*)&g[t * 4];
    float4 bv = *(const float4*)&b[t * 4];
    short4v o;
    o[0] = (short)__bfloat16_as_ushort(__float2bfloat16(d0 * rstd * gv.x + bv.x));
    o[1] = (short)__bfloat16_as_ushort(__float2bfloat16(d1 * rstd * gv.y + bv.y));
    o[2] = (short)__bfloat16_as_ushort(__float2bfloat16(d2 * rstd * gv.z + bv.z));
    o[3] = (short)__bfloat16_as_ushort(__float2bfloat16(d3 * rstd * gv.w + bv.w));
    *(short4v*)&((unsigned short*)y)[base + t * 4] = o;
}

// ---- LayerNorm, bf16 in -> bf16 out ----
__global__ __launch_bounds__(192) void ln_bf(const bf16* __restrict__ x,
                                             const float* __restrict__ g,
                                             const float* __restrict__ b,
                                             bf16* __restrict__ y) {
    __shared__ float red[3];
    size_t base = (size_t)blockIdx.x * 768;
    int t = threadIdx.x;
    short4v w = *(const short4v*)&((const unsigned short*)x)[base + t * 4];
    float v0 = bfbits2f((unsigned short)w[0]), v1 = bfbits2f((unsigned short)w[1]);
    float v2 = bfbits2f((unsigned short)w[2]), v3 = bfbits2f((unsigned short)w[3]);
    float s = blk_sum3(v0 + v1 + v2 + v3, red);
    float mean = s * (1.0f / 768.0f);
    float d0 = v0 - mean, d1 = v1 - mean, d2 = v2 - mean, d3 = v3 - mean;
    float sq = blk_sum3(d0 * d0 + d1 * d1 + d2 * d2 + d3 * d3, red);
    float rstd = rsqrtf(sq * (1.0f / 768.0f) + 1e-6f);
    float4 gv = *(const float4*)&g[t * 4];
    float4 bv = *(const float4*)&b[t * 4];
    short4v o;
    o[0] = (short)__bfloat16_as_ushort(__float2bfloat16(d0 * rstd * gv.x + bv.x));
    o[1] = (short)__bfloat16_as_ushort(__float2bfloat16(d1 * rstd * gv.y + bv.y));
    o[2] = (short)__bfloat16_as_ushort(__float2bfloat16(d2 * rstd * gv.z + bv.z));
    o[3] = (short)__bfloat16_as_ushort(__float2bfloat16(d3 * rstd * gv.w + bv.w));
    *(short4v*)&((unsigned short*)y)[base + t * 4] = o;
}

// ---- f32 -> bf16 cast ----
__global__ __launch_bounds__(256) void cast_kernel(const float* __restrict__ s,
                                                   bf16* __restrict__ d, int n) {
    int i = blockIdx.x * 256 + threadIdx.x;
    if (i < n) d[i] = __float2bfloat16(s[i]);
}

// ---- concat K/Q/V biases into one [1920] f32 buffer ----
__global__ __launch_bounds__(256) void bias_cat(const float* __restrict__ bk,
                                                const float* __restrict__ bq,
                                                const float* __restrict__ bv,
                                                float* __restrict__ o) {
    int i = blockIdx.x * 256 + threadIdx.x;
    if (i < 768) o[i] = bk[i];
    else if (i < 1536) o[i] = bq[i - 768];
    else if (i < 1920) o[i] = bv[i - 1536];
}

// ---- bf16 transpose per batch: Y [768,3136] -> Xt [3136,768] ----
__global__ __launch_bounds__(256) void transp_k(const bf16* __restrict__ Y,
                                                bf16* __restrict__ Xt) {
    __shared__ unsigned short tile[64][65];
    const size_t LD = (size_t)768 * 3136;
    int n = blockIdx.z;
    int l0 = blockIdx.x * 64, d0 = blockIdx.y * 64;
    const unsigned short* Yp = (const unsigned short*)Y + (size_t)n * LD;
    unsigned short* Xp = (unsigned short*)Xt + (size_t)n * LD;
    int t = threadIdx.x;
#pragma unroll
    for (int j = 0; j < 2; j++) {
        int e = t + 256 * j;
        int dd = e >> 3, lg = (e & 7) * 8;
        short8 v = *(const short8*)&Yp[(size_t)(d0 + dd) * 3136 + l0 + lg];
#pragma unroll
        for (int u = 0; u < 8; u++) tile[dd][lg + u] = (unsigned short)v[u];
    }
    __syncthreads();
#pragma unroll
    for (int j = 0; j < 2; j++) {
        int e = t + 256 * j;
        int ll = e >> 3, dg = (e & 7) * 8;
        short8 v;
#pragma unroll
        for (int u = 0; u < 8; u++) v[u] = (short)tile[dg + u][ll];
        *(short8*)&Xp[(size_t)(l0 + ll) * 768 + d0 + dg] = v;
    }
}

// ============ 256x256 BK=64 double-buffered GEMM, counted vmcnt ============
// C[M,N] = A[M,K] * B[N,K]^T. 512 threads = 8 waves (2M x 4N). LDS 128 KiB dyn.
// Sync/vmcnt ledger identical to proven R5 structure; compute split into
// 4 phases/tile (k2-half x M-half quadrants), m201-style barrier pairs +
// setprio around each 16-MFMA cluster.
// MODE 0: split-KQV bf16 (N padded; store col<1920), +bias[col]
// MODE 2: C0=bf16, gelu(v + bias[col])
// MODE 3: C0=f32,  v + bias[col] + residb(bf16)[flat]
template <int MODE>
__global__ __launch_bounds__(512, 2) void gemm256(
    const bf16* __restrict__ A, const bf16* __restrict__ B,
    const float* __restrict__ bias, const void* __restrict__ resid,
    void* __restrict__ C0, void* __restrict__ C1, void* __restrict__ C2,
    int M, int N, int K) {
    extern __shared__ char smem[];
    const int tid = threadIdx.x;
    const int lane = tid & 63, wave = tid >> 6;

    // XCD-chunked bijective swizzle; bn fastest within a chunk
    const int nbn = gridDim.x;
    const int nwg = nbn * gridDim.y;
    const int orig = blockIdx.y * nbn + blockIdx.x;
    const int qq = nwg >> 3, rm = nwg & 7;
    const int xcd = orig & 7, pos = orig >> 3;
    const int work = (xcd < rm ? xcd * (qq + 1) : rm * (qq + 1) + (xcd - rm) * qq) + pos;
    const int bn = work % nbn, bm = work / nbn;

    const int wm = (wave >> 2) * 128, wn = (wave & 3) * 64;
    const int frow = lane & 15, fsb = lane >> 4, fxr = frow & 7;
    const int srow = lane >> 3, sslot = (lane & 7) ^ srow;
    const size_t rowB = (size_t)K * 2;
    const char* Ap = (const char*)A + (size_t)(bm * 256 + wave * 32 + srow) * rowB + sslot * 16;
    const char* Bp = (const char*)B + (size_t)(bn * 256 + wave * 32 + srow) * rowB + sslot * 16;
    char* lA = smem + wave * 32 * 128;           // + c*1024 + p*65536
    char* lB = smem + 32768 + wave * 32 * 128;

    f32x4 acc[8][4];
#pragma unroll
    for (int mi = 0; mi < 8; mi++)
#pragma unroll
        for (int ni = 0; ni < 4; ni++)
#pragma unroll
            for (int r = 0; r < 4; r++) acc[mi][ni][r] = 0.0f;

    auto stage = [&](int kt, int p) {
#pragma unroll
        for (int c = 0; c < 4; c++) {
            gload16(Ap + (size_t)c * 8 * rowB + (size_t)kt * 2, lA + p * 65536 + c * 1024);
            gload16(Bp + (size_t)c * 8 * rowB + (size_t)kt * 2, lB + p * 65536 + c * 1024);
        }
    };
    const int nt = K >> 6;   // K in {768, 3072}: nt >= 12
    stage(0, 0);
    stage(64, 1);
    for (int t = 0; t < nt; ++t) {
        // Drain this tile's 8 loads. Steady state: 16 outstanding (tiles t,t+1),
        // vmcnt(8) completes tile t, leaves t+1 in flight. LAST tile: only its
        // own 8 outstanding -> must drain to 0 (R4 race lesson).
        if (t == nt - 1)
            asm volatile("s_waitcnt vmcnt(0)" ::: "memory");
        else
            asm volatile("s_waitcnt vmcnt(8)" ::: "memory");
        __builtin_amdgcn_s_barrier();        // tile-t data visible block-wide
        __builtin_amdgcn_sched_barrier(0);
        const bf16* As = (const bf16*)(smem + (t & 1) * 65536);
        const bf16* Bs = (const bf16*)(smem + (t & 1) * 65536 + 32768);
#pragma unroll
        for (int k2 = 0; k2 < 2; k2++) {
            const int ko = ((k2 * 4 + fsb) ^ fxr) << 3;
            short8 bfv[4], af[4];
            // ---- phase (k2, M-low): read B[k2] + A-low, MFMA 16 ----
#pragma unroll
            for (int ni = 0; ni < 4; ni++)
                bfv[ni] = *(const short8*)&Bs[(wn + ni * 16 + frow) * 64 + ko];
#pragma unroll
            for (int i = 0; i < 4; i++)
                af[i] = *(const short8*)&As[(wm + i * 16 + frow) * 64 + ko];
            __builtin_amdgcn_sched_barrier(0);
            __builtin_amdgcn_s_barrier();
            __builtin_amdgcn_sched_barrier(0);
            __builtin_amdgcn_s_setprio(1);
#pragma unroll
            for (int i = 0; i < 4; i++)
#pragma unroll
                for (int ni = 0; ni < 4; ni++)
                    acc[i][ni] = __builtin_amdgcn_mfma_f32_16x16x32_bf16(
                        af[i], bfv[ni], acc[i][ni], 0, 0, 0);
            __builtin_amdgcn_s_setprio(0);
            __builtin_amdgcn_sched_barrier(0);
            __builtin_amdgcn_s_barrier();
            __builtin_amdgcn_sched_barrier(0);
            // ---- phase (k2, M-high): read A-high (reuse B regs), MFMA 16 ----
#pragma unroll
            for (int i = 0; i < 4; i++)
                af[i] = *(const short8*)&As[(wm + (4 + i) * 16 + frow) * 64 + ko];
            __builtin_amdgcn_sched_barrier(0);
            __builtin_amdgcn_s_barrier();
            __builtin_amdgcn_sched_barrier(0);
            __builtin_amdgcn_s_setprio(1);
#pragma unroll
            for (int i = 0; i < 4; i++)
#pragma unroll
                for (int ni = 0; ni < 4; ni++)
                    acc[4 + i][ni] = __builtin_amdgcn_mfma_f32_16x16x32_bf16(
                        af[i], bfv[ni], acc[4 + i][ni], 0, 0, 0);
            __builtin_amdgcn_s_setprio(0);
            __builtin_amdgcn_sched_barrier(0);
            __builtin_amdgcn_s_barrier();
            __builtin_amdgcn_sched_barrier(0);
        }
        // all waves past final phase barrier -> buffer (t&1) fully consumed
        if (t + 2 < nt) stage((t + 2) * 64, t & 1);
    }

    const unsigned short* Rb = (const unsigned short*)resid;
#pragma unroll
    for (int mi = 0; mi < 8; mi++)
#pragma unroll
        for (int ni = 0; ni < 4; ni++)
#pragma unroll
            for (int r = 0; r < 4; r++) {
                int row = bm * 256 + wm + mi * 16 + fsb * 4 + r;
                int col = bn * 256 + wn + ni * 16 + frow;
                float v = acc[mi][ni][r];
                if (MODE == 0) {
                    if (col < 1920) {
                        float o = v + bias[col];
                        if (col < 768)
                            ((bf16*)C0)[(size_t)row * 768 + col] = __float2bfloat16(o);
                        else if (col < 1536)
                            ((bf16*)C1)[(size_t)row * 768 + col - 768] = __float2bfloat16(o);
                        else
                            ((bf16*)C2)[(size_t)row * 384 + col - 1536] = __float2bfloat16(o);
                    }
                } else if (MODE == 2) {
                    ((bf16*)C0)[(size_t)row * N + col] =
                        __float2bfloat16(gelu_fast(v + bias[col]));
                } else {
                    size_t idx = (size_t)row * N + col;
                    ((float*)C0)[idx] = v + bias[col] + bfbits2f(Rb[idx]);
                }
            }
}

// ---- 128x128 GEMM (proven), kept for the Wr projection ----
// MODE 1: C0=bf16, v + bias[row] + residf(f32)[flat]
template <int MODE>
__global__ __launch_bounds__(256) void gemm_nk(
    const bf16* __restrict__ A, const bf16* __restrict__ B,
    const float* __restrict__ bias, const void* __restrict__ resid,
    void* __restrict__ C0, int M, int N, int K, long sB, long sC, long sR) {
    __shared__ bf16 As[128 * 64];
    __shared__ bf16 Bs[128 * 64];
    const int tid = threadIdx.x;
    const int lane = tid & 63, wave = tid >> 6;
    const int nbn = gridDim.x;
    const int nwg = nbn * gridDim.y;
    const int orig = blockIdx.y * nbn + blockIdx.x;
    const int qq = nwg >> 3, rm = nwg & 7;
    const int xcd = orig & 7, pos = orig >> 3;
    const int work = (xcd < rm ? xcd * (qq + 1) : rm * (qq + 1) + (xcd - rm) * qq) + pos;
    const int bn = work % nbn, bm = work / nbn;
    const int bz = blockIdx.z;

    const int wm = (wave >> 1) * 64, wn = (wave & 1) * 64;
    const int frow = lane & 15, fsb = lane >> 4, fxr = frow & 7;
    const int srow = lane >> 3, sslot = (lane & 7) ^ srow;
    const size_t rowB = (size_t)K * 2;
    const char* Ap = (const char*)A +
        ((size_t)bm * 128 + wave * 32 + srow) * rowB + (size_t)sslot * 16;
    const char* Bp = (const char*)(B + (size_t)bz * sB) +
        ((size_t)bn * 128 + wave * 32 + srow) * rowB + (size_t)sslot * 16;

    f32x4 acc[4][4];
#pragma unroll
    for (int mi = 0; mi < 4; mi++)
#pragma unroll
        for (int ni = 0; ni < 4; ni++)
#pragma unroll
            for (int r = 0; r < 4; r++) acc[mi][ni][r] = 0.0f;

    for (int kt = 0; kt < K; kt += 64) {
#pragma unroll
        for (int c = 0; c < 4; c++) {
            gload16(Ap + (size_t)c * 8 * rowB + (size_t)kt * 2, &As[(wave * 4 + c) * 512]);
            gload16(Bp + (size_t)c * 8 * rowB + (size_t)kt * 2, &Bs[(wave * 4 + c) * 512]);
        }
        __syncthreads();
#pragma unroll
        for (int k2 = 0; k2 < 2; k2++) {
            short8 af[4], bfv[4];
#pragma unroll
            for (int mi = 0; mi < 4; mi++) {
                int r = wm + mi * 16 + frow;
                af[mi] = *(const short8*)&As[r * 64 + (((k2 * 4 + fsb) ^ fxr) << 3)];
            }
#pragma unroll
            for (int ni = 0; ni < 4; ni++) {
                int r = wn + ni * 16 + frow;
                bfv[ni] = *(const short8*)&Bs[r * 64 + (((k2 * 4 + fsb) ^ fxr) << 3)];
            }
#pragma unroll
            for (int mi = 0; mi < 4; mi++)
#pragma unroll
                for (int ni = 0; ni < 4; ni++)
                    acc[mi][ni] = __builtin_amdgcn_mfma_f32_16x16x32_bf16(
                        af[mi], bfv[ni], acc[mi][ni], 0, 0, 0);
        }
        __syncthreads();
    }

    const float* Rf = (const float*)resid + (size_t)bz * sR;
#pragma unroll
    for (int mi = 0; mi < 4; mi++)
#pragma unroll
        for (int ni = 0; ni < 4; ni++)
#pragma unroll
            for (int r = 0; r < 4; r++) {
                int row = bm * 128 + wm + mi * 16 + (fsb << 2) + r;
                int col = bn * 128 + wn + ni * 16 + frow;
                if (col < N) {
                    float v = acc[mi][ni][r];
                    size_t idx = (size_t)row * N + col;
                    bf16* Cb = (bf16*)C0 + (size_t)bz * sC;
                    Cb[idx] = __float2bfloat16(v + bias[row] + Rf[idx]);
                }
            }
}

// ---- fused context: ctx_raw[nh,96,48] = sum_l exp(k[l,96]) outer v[l,48];
//      S[nh,96] = sum_l exp(k).  Raw (pre-softmax) Kt in. ----
__global__ __launch_bounds__(256) void context_k(const bf16* __restrict__ Kt,
                                                 const bf16* __restrict__ Vt,
                                                 float* __restrict__ ctx,
                                                 float* __restrict__ Sf) {
    __shared__ float ks[32][96];
    __shared__ float vs[32][48];
    int nh = blockIdx.y;
    int n = nh >> 3, h = nh & 7;
    int t = threadIdx.x;
    const unsigned short* kp = (const unsigned short*)Kt;
    const unsigned short* vp = (const unsigned short*)Vt;
    int a = t >> 4, bq = t & 15;
    float acc[6][3];
    float sacc[6];
#pragma unroll
    for (int i = 0; i < 6; i++) {
        sacc[i] = 0.f;
#pragma unroll
        for (int j = 0; j < 3; j++) acc[i][j] = 0.f;
    }
    int l0 = blockIdx.x * 448;
    for (int ls = l0; ls < l0 + 448; ls += 32) {
        __syncthreads();
#pragma unroll
        for (int j = 0; j < 6; j++) {
            int e = t + 256 * j;
            int row = e / 48, cp = e % 48;
            unsigned u = *(const unsigned*)&kp[((size_t)(n * 3136 + ls + row)) * 768 + h * 96 + cp * 2];
            ks[row][cp * 2] = __expf(bfbits2f((unsigned short)(u & 0xffff)));
            ks[row][cp * 2 + 1] = __expf(bfbits2f((unsigned short)(u >> 16)));
        }
#pragma unroll
        for (int j = 0; j < 3; j++) {
            int e = t + 256 * j;
            int row = e / 24, cp = e % 24;
            unsigned u = *(const unsigned*)&vp[((size_t)(n * 3136 + ls + row)) * 384 + h * 48 + cp * 2];
            vs[row][cp * 2] = bfbits2f((unsigned short)(u & 0xffff));
            vs[row][cp * 2 + 1] = bfbits2f((unsigned short)(u >> 16));
        }
        __syncthreads();
        for (int ll = 0; ll < 32; ll++) {
            float kv[6], vv[3];
#pragma unroll
            for (int i = 0; i < 6; i++) { kv[i] = ks[ll][a * 6 + i]; sacc[i] += kv[i]; }
#pragma unroll
            for (int j = 0; j < 3; j++) vv[j] = vs[ll][bq * 3 + j];
#pragma unroll
            for (int i = 0; i < 6; i++)
#pragma unroll
                for (int j = 0; j < 3; j++) acc[i][j] += kv[i] * vv[j];
        }
    }
    float* cb = ctx + (size_t)nh * 4608;
#pragma unroll
    for (int i = 0; i < 6; i++) {
#pragma unroll
        for (int j = 0; j < 3; j++)
            atomicAdd(&cb[(a * 6 + i) * 48 + bq * 3 + j], acc[i][j]);
        if (bq == 0) atomicAdd(&Sf[(size_t)nh * 96 + a * 6 + i], sacc[i]);
    }
}

// ---- normalize context rows by S ----
__global__ __launch_bounds__(256) void ctx_fin(float* __restrict__ ctx,
                                               const float* __restrict__ Sf) {
    int nh = blockIdx.x;
    __shared__ float sinv[96];
    if (threadIdx.x < 96) sinv[threadIdx.x] = 1.0f / Sf[(size_t)nh * 96 + threadIdx.x];
    __syncthreads();
    for (int e = threadIdx.x; e < 4608; e += 256)
        ctx[(size_t)nh * 4608 + e] *= sinv[e / 48];
}

// ---- att: per token, softmax(96 raw q) then ctx^T @ q, bf16 out ----
__global__ __launch_bounds__(256) void att_k(const float* __restrict__ ctx,
                                             const bf16* __restrict__ Qt,
                                             bf16* __restrict__ att) {
    __shared__ float cs[4608];
    int nh = blockIdx.y;
    int n = nh >> 3, h = nh & 7;
    for (int j = threadIdx.x; j < 4608; j += 256) cs[j] = ctx[(size_t)nh * 4608 + j];
    __syncthreads();
    int l = blockIdx.x * 256 + threadIdx.x;
    if (l >= 3136) return;
    const unsigned short* qp = (const unsigned short*)Qt + ((size_t)(n * 3136 + l)) * 768 + h * 96;
    float qv[96];
    float s = 0.f;
#pragma unroll
    for (int j = 0; j < 12; j++) {
        short8 w = *(const short8*)&qp[j * 8];
#pragma unroll
        for (int x = 0; x < 8; x++) {
            float e = __expf(bfbits2f((unsigned short)w[x]));
            qv[j * 8 + x] = e;
            s += e;
        }
    }
    float inv = 1.0f / s;
    unsigned short ov[48];
#pragma unroll
    for (int vb = 0; vb < 12; vb++) {
        f32x4 acc4;
        acc4[0] = acc4[1] = acc4[2] = acc4[3] = 0.f;
        for (int k = 0; k < 96; k++) {
            f32x4 c4 = *(const f32x4*)&cs[k * 48 + vb * 4];
            float q = qv[k];
#pragma unroll
            for (int x = 0; x < 4; x++) acc4[x] += c4[x] * q;
        }
#pragma unroll
        for (int x = 0; x < 4; x++)
            ov[vb * 4 + x] = __bfloat16_as_ushort(__float2bfloat16(acc4[x] * inv));
    }
    unsigned short* op = (unsigned short*)att + ((size_t)n * 3200 + l) * 384 + h * 48;
#pragma unroll
    for (int j = 0; j < 6; j++) *(short8*)&op[j * 8] = *(short8*)&ov[j * 8];
}

extern "C" void kernel_launch(void* const* d_in, const int* in_sizes, int n_in,
                              void* d_out, int out_size, void* d_ws, size_t ws_size,
                              hipStream_t stream) {
    (void)in_sizes; (void)n_in; (void)out_size; (void)ws_size;
    const float* x     = (const float*)d_in[0];
    const float* ln1_g = (const float*)d_in[1];
    const float* ln1_b = (const float*)d_in[2];
    const float* Wk    = (const float*)d_in[3];
    const float* bk    = (const float*)d_in[4];
    const float* Wq    = (const float*)d_in[5];
    const float* bq    = (const float*)d_in[6];
    const float* Wv    = (const float*)d_in[7];
    const float* bv    = (const float*)d_in[8];
    const float* Wr    = (const float*)d_in[9];
    const float* br    = (const float*)d_in[10];
    const float* ln2_g = (const float*)d_in[11];
    const float* ln2_b = (const float*)d_in[12];
    const float* W1    = (const float*)d_in[13];
    const float* b1    = (const float*)d_in[14];
    const float* W2    = (const float*)d_in[15];
    const float* b2    = (const float*)d_in[16];

    const int Nb = 16, L = 3136;
    const size_t LD = (size_t)L * 768;
    const size_t sz77 = (size_t)50176 * 768 * 2;

    char* w = (char*)d_ws;
    size_t off = 0;
    auto alloc = [&](size_t bytes) {
        char* p = w + off;
        off = (off + bytes + 255) & ~(size_t)255;
        return p;
    };
    bf16* Ybf  = (bf16*)alloc(sz77);                       // Hbf rgn 0
    bf16* Xt   = (bf16*)alloc(sz77);                       // Hbf rgn 1 (ctx/S alias)
    bf16* Kt   = (bf16*)alloc(sz77);                       // Hbf rgn 2
    bf16* Qt   = (bf16*)alloc(sz77);                       // Hbf rgn 3
    bf16* Vt   = (bf16*)alloc((size_t)50176 * 384 * 2);    // Y2bf rgn
    bf16* attb = (bf16*)alloc((size_t)16 * 3200 * 384 * 2);
    bf16* x1   = (bf16*)alloc(sz77);
    bf16* Wkqv_bf = (bf16*)alloc((size_t)2048 * 768 * 2);  // padded to 2048 rows
    bf16* Wr_bf = (bf16*)alloc((size_t)768 * 384 * 2);
    bf16* W1_bf = (bf16*)alloc((size_t)3072 * 768 * 2);
    bf16* W2_bf = (bf16*)alloc((size_t)768 * 3072 * 2);
    float* bkqv = (float*)alloc((size_t)1920 * 4);
    // ctx + S alias Xt (Xt dead after KQV gemm; region dead before MLP1)
    float* ctx = (float*)Xt;
    float* Sf  = (float*)((char*)Xt + 4718592);
    bf16* Hbf  = Ybf;    // [50176,3072] spans rgns 0-3
    bf16* Y2bf = Vt;     // spills into attb (dead by then)

    auto castw = [&](const float* s, bf16* dp, int n) {
        cast_kernel<<<(n + 255) / 256, 256, 0, stream>>>(s, dp, n);
    };
    hipMemsetAsync(Wkqv_bf + (size_t)1920 * 768, 0, (size_t)128 * 768 * 2, stream);
    castw(Wk, Wkqv_bf, 768 * 768);
    castw(Wq, Wkqv_bf + 768 * 768, 768 * 768);
    castw(Wv, Wkqv_bf + 1536 * 768, 384 * 768);
    castw(Wr, Wr_bf, 768 * 384);
    castw(W1, W1_bf, 3072 * 768);
    castw(W2, W2_bf, 768 * 3072);
    bias_cat<<<8, 256, 0, stream>>>(bk, bq, bv, bkqv);

    hipFuncSetAttribute((const void*)gemm256<0>,
                        hipFuncAttributeMaxDynamicSharedMemorySize, 131072);
    hipFuncSetAttribute((const void*)gemm256<2>,
                        hipFuncAttributeMaxDynamicSharedMemorySize, 131072);
    hipFuncSetAttribute((const void*)gemm256<3>,
                        hipFuncAttributeMaxDynamicSharedMemorySize, 131072);

    // LN1: x -> Ybf, then transpose -> Xt [n*3136, 768]
    ln_f32<<<Nb * L, 192, 0, stream>>>(x, ln1_g, ln1_b, Ybf);
    transp_k<<<dim3(49, 12, 16), 256, 0, stream>>>(Ybf, Xt);

    // fused K/Q/V projection (N padded 1920->2048), split-store raw K/Q/V
    gemm256<0><<<dim3(8, 196), 512, 131072, stream>>>(
        Xt, Wkqv_bf, bkqv, nullptr, Kt, Qt, Vt, 50176, 2048, 768);

    // attention middle: exp-fused context + normalize + softmax-fused att
    hipMemsetAsync(ctx, 0, 4718592 + 49152, stream);
    context_k<<<dim3(7, 128), 256, 0, stream>>>(Kt, Vt, ctx, Sf);
    ctx_fin<<<128, 256, 0, stream>>>(ctx, Sf);
    att_k<<<dim3(13, 128), 256, 0, stream>>>(ctx, Qt, attb);

    // Wr projection + residual (flat add, f32 x) -> x1 bf16
    gemm_nk<1><<<dim3(25, 6, 16), 256, 0, stream>>>(
        Wr_bf, attb, br, x, x1, 768, 3136, 384,
        (long)3200 * 384, (long)LD, (long)LD);

    // LN2: x1 -> Y2bf
    ln_bf<<<Nb * L, 192, 0, stream>>>(x1, ln2_g, ln2_b, Y2bf);

    // MLP1: [50176,3072] = Y2 @ W1^T, +b1, gelu, bf16
    gemm256<2><<<dim3(12, 196), 512, 131072, stream>>>(
        Y2bf, W1_bf, b1, nullptr, Hbf, nullptr, nullptr, 50176, 3072, 768);
    // MLP2: d_out(f32) = H @ W2^T + b2 + x1
    gemm256<3><<<dim3(3, 196), 512, 131072, stream>>>(
        Hbf, W2_bf, b2, x1, d_out, nullptr, nullptr, 50176, 768, 3072);
}

// Round 7
// 1381.170 us; speedup vs baseline: 1.0515x; 1.0515x over previous
//
#include <hip/hip_runtime.h>
#include <hip/hip_bf16.h>

using bf16 = __hip_bfloat16;
typedef __attribute__((ext_vector_type(8))) short short8;
typedef __attribute__((ext_vector_type(4))) short short4v;
typedef __attribute__((ext_vector_type(4))) float f32x4;

__device__ __forceinline__ float bfbits2f(unsigned short h) {
    unsigned v = (unsigned)h << 16;
    return __uint_as_float(v);
}

__device__ __forceinline__ void gload16(const void* g, void* l) {
    __builtin_amdgcn_global_load_lds(
        (const __attribute__((address_space(1))) unsigned int*)g,
        (__attribute__((address_space(3))) unsigned int*)l, 16, 0, 0);
}

// tanh-form GELU: ~8 VALU; |diff vs exact erf-GELU| <= ~3e-3
__device__ __forceinline__ float gelu_fast(float x) {
    float x2 = x * x;
    float u = x * __builtin_fmaf(0.07135481f, x2, 1.59576912f);
    float e = __expf(u);
    return x - x * __builtin_amdgcn_rcpf(e + 1.0f);
}

// ---- block reduce over 3 waves (192 threads) ----
__device__ __forceinline__ float blk_sum3(float v, float* red) {
#pragma unroll
    for (int o = 32; o > 0; o >>= 1) v += __shfl_down(v, o, 64);
    int wv = threadIdx.x >> 6;
    __syncthreads();
    if ((threadIdx.x & 63) == 0) red[wv] = v;
    __syncthreads();
    return red[0] + red[1] + red[2];
}

// ---- LayerNorm over D=768, one block per row, f32 in -> bf16 out ----
__global__ __launch_bounds__(192) void ln_f32(const float* __restrict__ x,
                                              const float* __restrict__ g,
                                              const float* __restrict__ b,
                                              bf16* __restrict__ y) {
    __shared__ float red[3];
    size_t base = (size_t)blockIdx.x * 768;
    int t = threadIdx.x;
    float4 v = *(const float4*)&x[base + t * 4];
    float s = blk_sum3(v.x + v.y + v.z + v.w, red);
    float mean = s * (1.0f / 768.0f);
    float d0 = v.x - mean, d1 = v.y - mean, d2 = v.z - mean, d3 = v.w - mean;
    float sq = blk_sum3(d0 * d0 + d1 * d1 + d2 * d2 + d3 * d3, red);
    float rstd = rsqrtf(sq * (1.0f / 768.0f) + 1e-6f);
    float4 gv = *(const float4*)&g[t * 4];
    float4 bv = *(const float4*)&b[t * 4];
    short4v o;
    o[0] = (short)__bfloat16_as_ushort(__float2bfloat16(d0 * rstd * gv.x + bv.x));
    o[1] = (short)__bfloat16_as_ushort(__float2bfloat16(d1 * rstd * gv.y + bv.y));
    o[2] = (short)__bfloat16_as_ushort(__float2bfloat16(d2 * rstd * gv.z + bv.z));
    o[3] = (short)__bfloat16_as_ushort(__float2bfloat16(d3 * rstd * gv.w + bv.w));
    *(short4v*)&((unsigned short*)y)[base + t * 4] = o;
}

// ---- LayerNorm, bf16 in -> bf16 out ----
__global__ __launch_bounds__(192) void ln_bf(const bf16* __restrict__ x,
                                             const float* __restrict__ g,
                                             const float* __restrict__ b,
                                             bf16* __restrict__ y) {
    __shared__ float red[3];
    size_t base = (size_t)blockIdx.x * 768;
    int t = threadIdx.x;
    short4v w = *(const short4v*)&((const unsigned short*)x)[base + t * 4];
    float v0 = bfbits2f((unsigned short)w[0]), v1 = bfbits2f((unsigned short)w[1]);
    float v2 = bfbits2f((unsigned short)w[2]), v3 = bfbits2f((unsigned short)w[3]);
    float s = blk_sum3(v0 + v1 + v2 + v3, red);
    float mean = s * (1.0f / 768.0f);
    float d0 = v0 - mean, d1 = v1 - mean, d2 = v2 - mean, d3 = v3 - mean;
    float sq = blk_sum3(d0 * d0 + d1 * d1 + d2 * d2 + d3 * d3, red);
    float rstd = rsqrtf(sq * (1.0f / 768.0f) + 1e-6f);
    float4 gv = *(const float4*)&g[t * 4];
    float4 bv = *(const float4*)&b[t * 4];
    short4v o;
    o[0] = (short)__bfloat16_as_ushort(__float2bfloat16(d0 * rstd * gv.x + bv.x));
    o[1] = (short)__bfloat16_as_ushort(__float2bfloat16(d1 * rstd * gv.y + bv.y));
    o[2] = (short)__bfloat16_as_ushort(__float2bfloat16(d2 * rstd * gv.z + bv.z));
    o[3] = (short)__bfloat16_as_ushort(__float2bfloat16(d3 * rstd * gv.w + bv.w));
    *(short4v*)&((unsigned short*)y)[base + t * 4] = o;
}

// ---- fused prep: weight casts (+KQV pad-zero) + bias concat, one launch ----
__global__ __launch_bounds__(256) void prep(
    const float* __restrict__ Wk, const float* __restrict__ Wq,
    const float* __restrict__ Wv, const float* __restrict__ Wr,
    const float* __restrict__ W1, const float* __restrict__ W2,
    const float* __restrict__ bk, const float* __restrict__ bq,
    const float* __restrict__ bv,
    bf16* __restrict__ Wkqv, bf16* __restrict__ Wrb,
    bf16* __restrict__ W1b, bf16* __restrict__ W2b, float* __restrict__ bkqv) {
    int i = blockIdx.x * 256 + threadIdx.x;
    const int nKQV = 2048 * 768, nWr = 768 * 384, nW1 = 3072 * 768, nW2 = 768 * 3072;
    if (i < nKQV) {
        int r = i / 768;
        float v = 0.f;
        if (r < 768) v = Wk[i];
        else if (r < 1536) v = Wq[i - 768 * 768];
        else if (r < 1920) v = Wv[i - 1536 * 768];
        Wkqv[i] = __float2bfloat16(v);
        return;
    }
    i -= nKQV;
    if (i < nWr) { Wrb[i] = __float2bfloat16(Wr[i]); return; }
    i -= nWr;
    if (i < nW1) { W1b[i] = __float2bfloat16(W1[i]); return; }
    i -= nW1;
    if (i < nW2) { W2b[i] = __float2bfloat16(W2[i]); return; }
    i -= nW2;
    if (i < 1920) bkqv[i] = (i < 768) ? bk[i] : (i < 1536 ? bq[i - 768] : bv[i - 1536]);
}

// ---- bf16 transpose per batch: Y [768,3136] -> Xt [3136,768] ----
__global__ __launch_bounds__(256) void transp_k(const bf16* __restrict__ Y,
                                                bf16* __restrict__ Xt) {
    __shared__ unsigned short tile[64][65];
    const size_t LD = (size_t)768 * 3136;
    int n = blockIdx.z;
    int l0 = blockIdx.x * 64, d0 = blockIdx.y * 64;
    const unsigned short* Yp = (const unsigned short*)Y + (size_t)n * LD;
    unsigned short* Xp = (unsigned short*)Xt + (size_t)n * LD;
    int t = threadIdx.x;
#pragma unroll
    for (int j = 0; j < 2; j++) {
        int e = t + 256 * j;
        int dd = e >> 3, lg = (e & 7) * 8;
        short8 v = *(const short8*)&Yp[(size_t)(d0 + dd) * 3136 + l0 + lg];
#pragma unroll
        for (int u = 0; u < 8; u++) tile[dd][lg + u] = (unsigned short)v[u];
    }
    __syncthreads();
#pragma unroll
    for (int j = 0; j < 2; j++) {
        int e = t + 256 * j;
        int ll = e >> 3, dg = (e & 7) * 8;
        short8 v;
#pragma unroll
        for (int u = 0; u < 8; u++) v[u] = (short)tile[dg + u][ll];
        *(short8*)&Xp[(size_t)(l0 + ll) * 768 + d0 + dg] = v;
    }
}

// ============ 256x256 BK=64 double-buffered GEMM, counted vmcnt ============
// C[M,N] = A[M,K] * B[N,K]^T. 512 threads = 8 waves (2M x 4N). LDS 128 KiB dyn.
// Proven R5 schedule: vmcnt(8) steady / vmcnt(0) last tile, 2 barriers/tile.
// MODE 0: split-KQV bf16 (N padded; store col<1920), +bias[col]
// MODE 2: C0=bf16, gelu(v + bias[col])
// MODE 3: C0=f32,  v + bias[col] + residb(bf16)[flat]
template <int MODE>
__global__ __launch_bounds__(512, 2) void gemm256(
    const bf16* __restrict__ A, const bf16* __restrict__ B,
    const float* __restrict__ bias, const void* __restrict__ resid,
    void* __restrict__ C0, void* __restrict__ C1, void* __restrict__ C2,
    int M, int N, int K) {
    extern __shared__ char smem[];
    const int tid = threadIdx.x;
    const int lane = tid & 63, wave = tid >> 6;

    // XCD-chunked bijective swizzle; bn fastest within a chunk
    const int nbn = gridDim.x;
    const int nwg = nbn * gridDim.y;
    const int orig = blockIdx.y * nbn + blockIdx.x;
    const int qq = nwg >> 3, rm = nwg & 7;
    const int xcd = orig & 7, pos = orig >> 3;
    const int work = (xcd < rm ? xcd * (qq + 1) : rm * (qq + 1) + (xcd - rm) * qq) + pos;
    const int bn = work % nbn, bm = work / nbn;

    const int wm = (wave >> 2) * 128, wn = (wave & 3) * 64;
    const int frow = lane & 15, fsb = lane >> 4, fxr = frow & 7;
    const int srow = lane >> 3, sslot = (lane & 7) ^ srow;
    const size_t rowB = (size_t)K * 2;
    const char* Ap = (const char*)A + (size_t)(bm * 256 + wave * 32 + srow) * rowB + sslot * 16;
    const char* Bp = (const char*)B + (size_t)(bn * 256 + wave * 32 + srow) * rowB + sslot * 16;
    char* lA = smem + wave * 32 * 128;           // + c*1024 + p*65536
    char* lB = smem + 32768 + wave * 32 * 128;

    f32x4 acc[8][4];
#pragma unroll
    for (int mi = 0; mi < 8; mi++)
#pragma unroll
        for (int ni = 0; ni < 4; ni++)
#pragma unroll
            for (int r = 0; r < 4; r++) acc[mi][ni][r] = 0.0f;

    auto stage = [&](int kt, int p) {
#pragma unroll
        for (int c = 0; c < 4; c++) {
            gload16(Ap + (size_t)c * 8 * rowB + (size_t)kt * 2, lA + p * 65536 + c * 1024);
            gload16(Bp + (size_t)c * 8 * rowB + (size_t)kt * 2, lB + p * 65536 + c * 1024);
        }
    };
    const int nt = K >> 6;   // K in {768, 3072}: nt >= 12
    stage(0, 0);
    stage(64, 1);
    for (int t = 0; t < nt; ++t) {
        // Drain this tile's 8 loads. Steady state: 16 outstanding (tiles t,t+1),
        // vmcnt(8) completes tile t, leaves t+1 in flight. LAST tile: only its
        // own 8 outstanding -> must drain to 0 (R4 race lesson).
        if (t == nt - 1)
            asm volatile("s_waitcnt vmcnt(0)" ::: "memory");
        else
            asm volatile("s_waitcnt vmcnt(8)" ::: "memory");
        __builtin_amdgcn_s_barrier();        // tile-t data visible block-wide
        asm volatile("" ::: "memory");
        const bf16* As = (const bf16*)(smem + (t & 1) * 65536);
        const bf16* Bs = (const bf16*)(smem + (t & 1) * 65536 + 32768);
#pragma unroll
        for (int k2 = 0; k2 < 2; k2++) {
            const int ko = ((k2 * 4 + fsb) ^ fxr) << 3;
            short8 bfv[4];
#pragma unroll
            for (int ni = 0; ni < 4; ni++)
                bfv[ni] = *(const short8*)&Bs[(wn + ni * 16 + frow) * 64 + ko];
#pragma unroll
            for (int half = 0; half < 2; half++) {
                short8 af[4];
#pragma unroll
                for (int i = 0; i < 4; i++)
                    af[i] = *(const short8*)&As[(wm + (half * 4 + i) * 16 + frow) * 64 + ko];
#pragma unroll
                for (int i = 0; i < 4; i++)
#pragma unroll
                    for (int ni = 0; ni < 4; ni++)
                        acc[half * 4 + i][ni] = __builtin_amdgcn_mfma_f32_16x16x32_bf16(
                            af[i], bfv[ni], acc[half * 4 + i][ni], 0, 0, 0);
            }
        }
        asm volatile("" ::: "memory");
        __builtin_amdgcn_s_barrier();        // all reads of buf (t&1) complete
        if (t + 2 < nt) stage((t + 2) * 64, t & 1);
    }

    const unsigned short* Rb = (const unsigned short*)resid;
#pragma unroll
    for (int mi = 0; mi < 8; mi++)
#pragma unroll
        for (int ni = 0; ni < 4; ni++)
#pragma unroll
            for (int r = 0; r < 4; r++) {
                int row = bm * 256 + wm + mi * 16 + fsb * 4 + r;
                int col = bn * 256 + wn + ni * 16 + frow;
                float v = acc[mi][ni][r];
                if (MODE == 0) {
                    if (col < 1920) {
                        float o = v + bias[col];
                        if (col < 768)
                            ((bf16*)C0)[(size_t)row * 768 + col] = __float2bfloat16(o);
                        else if (col < 1536)
                            ((bf16*)C1)[(size_t)row * 768 + col - 768] = __float2bfloat16(o);
                        else
                            ((bf16*)C2)[(size_t)row * 384 + col - 1536] = __float2bfloat16(o);
                    }
                } else if (MODE == 2) {
                    ((bf16*)C0)[(size_t)row * N + col] =
                        __float2bfloat16(gelu_fast(v + bias[col]));
                } else {
                    size_t idx = (size_t)row * N + col;
                    ((float*)C0)[idx] = v + bias[col] + bfbits2f(Rb[idx]);
                }
            }
}

// ---- 128x128 GEMM (proven), kept for the Wr projection ----
// MODE 1: C0=bf16, v + bias[row] + residf(f32)[flat]
template <int MODE>
__global__ __launch_bounds__(256) void gemm_nk(
    const bf16* __restrict__ A, const bf16* __restrict__ B,
    const float* __restrict__ bias, const void* __restrict__ resid,
    void* __restrict__ C0, int M, int N, int K, long sB, long sC, long sR) {
    __shared__ bf16 As[128 * 64];
    __shared__ bf16 Bs[128 * 64];
    const int tid = threadIdx.x;
    const int lane = tid & 63, wave = tid >> 6;
    const int nbn = gridDim.x;
    const int nwg = nbn * gridDim.y;
    const int orig = blockIdx.y * nbn + blockIdx.x;
    const int qq = nwg >> 3, rm = nwg & 7;
    const int xcd = orig & 7, pos = orig >> 3;
    const int work = (xcd < rm ? xcd * (qq + 1) : rm * (qq + 1) + (xcd - rm) * qq) + pos;
    const int bn = work % nbn, bm = work / nbn;
    const int bz = blockIdx.z;

    const int wm = (wave >> 1) * 64, wn = (wave & 1) * 64;
    const int frow = lane & 15, fsb = lane >> 4, fxr = frow & 7;
    const int srow = lane >> 3, sslot = (lane & 7) ^ srow;
    const size_t rowB = (size_t)K * 2;
    const char* Ap = (const char*)A +
        ((size_t)bm * 128 + wave * 32 + srow) * rowB + (size_t)sslot * 16;
    const char* Bp = (const char*)(B + (size_t)bz * sB) +
        ((size_t)bn * 128 + wave * 32 + srow) * rowB + (size_t)sslot * 16;

    f32x4 acc[4][4];
#pragma unroll
    for (int mi = 0; mi < 4; mi++)
#pragma unroll
        for (int ni = 0; ni < 4; ni++)
#pragma unroll
            for (int r = 0; r < 4; r++) acc[mi][ni][r] = 0.0f;

    for (int kt = 0; kt < K; kt += 64) {
#pragma unroll
        for (int c = 0; c < 4; c++) {
            gload16(Ap + (size_t)c * 8 * rowB + (size_t)kt * 2, &As[(wave * 4 + c) * 512]);
            gload16(Bp + (size_t)c * 8 * rowB + (size_t)kt * 2, &Bs[(wave * 4 + c) * 512]);
        }
        __syncthreads();
#pragma unroll
        for (int k2 = 0; k2 < 2; k2++) {
            short8 af[4], bfv[4];
#pragma unroll
            for (int mi = 0; mi < 4; mi++) {
                int r = wm + mi * 16 + frow;
                af[mi] = *(const short8*)&As[r * 64 + (((k2 * 4 + fsb) ^ fxr) << 3)];
            }
#pragma unroll
            for (int ni = 0; ni < 4; ni++) {
                int r = wn + ni * 16 + frow;
                bfv[ni] = *(const short8*)&Bs[r * 64 + (((k2 * 4 + fsb) ^ fxr) << 3)];
            }
#pragma unroll
            for (int mi = 0; mi < 4; mi++)
#pragma unroll
                for (int ni = 0; ni < 4; ni++)
                    acc[mi][ni] = __builtin_amdgcn_mfma_f32_16x16x32_bf16(
                        af[mi], bfv[ni], acc[mi][ni], 0, 0, 0);
        }
        __syncthreads();
    }

    const float* Rf = (const float*)resid + (size_t)bz * sR;
#pragma unroll
    for (int mi = 0; mi < 4; mi++)
#pragma unroll
        for (int ni = 0; ni < 4; ni++)
#pragma unroll
            for (int r = 0; r < 4; r++) {
                int row = bm * 128 + wm + mi * 16 + (fsb << 2) + r;
                int col = bn * 128 + wn + ni * 16 + frow;
                if (col < N) {
                    float v = acc[mi][ni][r];
                    size_t idx = (size_t)row * N + col;
                    bf16* Cb = (bf16*)C0 + (size_t)bz * sC;
                    Cb[idx] = __float2bfloat16(v + bias[row] + Rf[idx]);
                }
            }
}

// ---- fused context: ctx_raw[nh,96,48] = sum_l exp(k[l,96]) outer v[l,48];
//      S[nh,96] = sum_l exp(k).  Raw (pre-softmax) Kt in. ----
__global__ __launch_bounds__(256) void context_k(const bf16* __restrict__ Kt,
                                                 const bf16* __restrict__ Vt,
                                                 float* __restrict__ ctx,
                                                 float* __restrict__ Sf) {
    __shared__ float ks[32][96];
    __shared__ float vs[32][48];
    int nh = blockIdx.y;
    int n = nh >> 3, h = nh & 7;
    int t = threadIdx.x;
    const unsigned short* kp = (const unsigned short*)Kt;
    const unsigned short* vp = (const unsigned short*)Vt;
    int a = t >> 4, bq = t & 15;
    float acc[6][3];
    float sacc[6];
#pragma unroll
    for (int i = 0; i < 6; i++) {
        sacc[i] = 0.f;
#pragma unroll
        for (int j = 0; j < 3; j++) acc[i][j] = 0.f;
    }
    int l0 = blockIdx.x * 448;
    for (int ls = l0; ls < l0 + 448; ls += 32) {
        __syncthreads();
#pragma unroll
        for (int j = 0; j < 6; j++) {
            int e = t + 256 * j;
            int row = e / 48, cp = e % 48;
            unsigned u = *(const unsigned*)&kp[((size_t)(n * 3136 + ls + row)) * 768 + h * 96 + cp * 2];
            ks[row][cp * 2] = __expf(bfbits2f((unsigned short)(u & 0xffff)));
            ks[row][cp * 2 + 1] = __expf(bfbits2f((unsigned short)(u >> 16)));
        }
#pragma unroll
        for (int j = 0; j < 3; j++) {
            int e = t + 256 * j;
            int row = e / 24, cp = e % 24;
            unsigned u = *(const unsigned*)&vp[((size_t)(n * 3136 + ls + row)) * 384 + h * 48 + cp * 2];
            vs[row][cp * 2] = bfbits2f((unsigned short)(u & 0xffff));
            vs[row][cp * 2 + 1] = bfbits2f((unsigned short)(u >> 16));
        }
        __syncthreads();
        for (int ll = 0; ll < 32; ll++) {
            float kv[6], vv[3];
#pragma unroll
            for (int i = 0; i < 6; i++) { kv[i] = ks[ll][a * 6 + i]; sacc[i] += kv[i]; }
#pragma unroll
            for (int j = 0; j < 3; j++) vv[j] = vs[ll][bq * 3 + j];
#pragma unroll
            for (int i = 0; i < 6; i++)
#pragma unroll
                for (int j = 0; j < 3; j++) acc[i][j] += kv[i] * vv[j];
        }
    }
    float* cb = ctx + (size_t)nh * 4608;
#pragma unroll
    for (int i = 0; i < 6; i++) {
#pragma unroll
        for (int j = 0; j < 3; j++)
            atomicAdd(&cb[(a * 6 + i) * 48 + bq * 3 + j], acc[i][j]);
        if (bq == 0) atomicAdd(&Sf[(size_t)nh * 96 + a * 6 + i], sacc[i]);
    }
}

// ---- att: normalize ctx by S while loading to LDS, per-token softmax(q),
//      then ctx^T @ q, bf16 out ----
__global__ __launch_bounds__(256) void att_k(const float* __restrict__ ctx,
                                             const float* __restrict__ Sf,
                                             const bf16* __restrict__ Qt,
                                             bf16* __restrict__ att) {
    __shared__ float cs[4608];
    __shared__ float sinv[96];
    int nh = blockIdx.y;
    int n = nh >> 3, h = nh & 7;
    if (threadIdx.x < 96)
        sinv[threadIdx.x] = 1.0f / Sf[(size_t)nh * 96 + threadIdx.x];
    __syncthreads();
    for (int j = threadIdx.x; j < 4608; j += 256)
        cs[j] = ctx[(size_t)nh * 4608 + j] * sinv[j / 48];
    __syncthreads();
    int l = blockIdx.x * 256 + threadIdx.x;
    if (l >= 3136) return;
    const unsigned short* qp = (const unsigned short*)Qt + ((size_t)(n * 3136 + l)) * 768 + h * 96;
    float qv[96];
    float s = 0.f;
#pragma unroll
    for (int j = 0; j < 12; j++) {
        short8 w = *(const short8*)&qp[j * 8];
#pragma unroll
        for (int x = 0; x < 8; x++) {
            float e = __expf(bfbits2f((unsigned short)w[x]));
            qv[j * 8 + x] = e;
            s += e;
        }
    }
    float inv = 1.0f / s;
    unsigned short ov[48];
#pragma unroll
    for (int vb = 0; vb < 12; vb++) {
        f32x4 acc4;
        acc4[0] = acc4[1] = acc4[2] = acc4[3] = 0.f;
        for (int k = 0; k < 96; k++) {
            f32x4 c4 = *(const f32x4*)&cs[k * 48 + vb * 4];
            float q = qv[k];
#pragma unroll
            for (int x = 0; x < 4; x++) acc4[x] += c4[x] * q;
        }
#pragma unroll
        for (int x = 0; x < 4; x++)
            ov[vb * 4 + x] = __bfloat16_as_ushort(__float2bfloat16(acc4[x] * inv));
    }
    unsigned short* op = (unsigned short*)att + ((size_t)n * 3200 + l) * 384 + h * 48;
#pragma unroll
    for (int j = 0; j < 6; j++) *(short8*)&op[j * 8] = *(short8*)&ov[j * 8];
}

extern "C" void kernel_launch(void* const* d_in, const int* in_sizes, int n_in,
                              void* d_out, int out_size, void* d_ws, size_t ws_size,
                              hipStream_t stream) {
    (void)in_sizes; (void)n_in; (void)out_size; (void)ws_size;
    const float* x     = (const float*)d_in[0];
    const float* ln1_g = (const float*)d_in[1];
    const float* ln1_b = (const float*)d_in[2];
    const float* Wk    = (const float*)d_in[3];
    const float* bk    = (const float*)d_in[4];
    const float* Wq    = (const float*)d_in[5];
    const float* bq    = (const float*)d_in[6];
    const float* Wv    = (const float*)d_in[7];
    const float* bv    = (const float*)d_in[8];
    const float* Wr    = (const float*)d_in[9];
    const float* br    = (const float*)d_in[10];
    const float* ln2_g = (const float*)d_in[11];
    const float* ln2_b = (const float*)d_in[12];
    const float* W1    = (const float*)d_in[13];
    const float* b1    = (const float*)d_in[14];
    const float* W2    = (const float*)d_in[15];
    const float* b2    = (const float*)d_in[16];

    const int Nb = 16, L = 3136;
    const size_t LD = (size_t)L * 768;
    const size_t sz77 = (size_t)50176 * 768 * 2;

    char* w = (char*)d_ws;
    size_t off = 0;
    auto alloc = [&](size_t bytes) {
        char* p = w + off;
        off = (off + bytes + 255) & ~(size_t)255;
        return p;
    };
    bf16* Ybf  = (bf16*)alloc(sz77);                       // Hbf rgn 0
    bf16* Xt   = (bf16*)alloc(sz77);                       // Hbf rgn 1 (ctx/S alias)
    bf16* Kt   = (bf16*)alloc(sz77);                       // Hbf rgn 2
    bf16* Qt   = (bf16*)alloc(sz77);                       // Hbf rgn 3
    bf16* Vt   = (bf16*)alloc((size_t)50176 * 384 * 2);    // Y2bf rgn
    bf16* attb = (bf16*)alloc((size_t)16 * 3200 * 384 * 2);
    bf16* x1   = (bf16*)alloc(sz77);
    bf16* Wkqv_bf = (bf16*)alloc((size_t)2048 * 768 * 2);  // padded to 2048 rows
    bf16* Wr_bf = (bf16*)alloc((size_t)768 * 384 * 2);
    bf16* W1_bf = (bf16*)alloc((size_t)3072 * 768 * 2);
    bf16* W2_bf = (bf16*)alloc((size_t)768 * 3072 * 2);
    float* bkqv = (float*)alloc((size_t)1920 * 4);
    // ctx + S alias Xt (Xt dead after KQV gemm; region dead before MLP1)
    float* ctx = (float*)Xt;
    float* Sf  = (float*)((char*)Xt + 4718592);
    bf16* Hbf  = Ybf;    // [50176,3072] spans rgns 0-3
    bf16* Y2bf = Vt;     // spills into attb (dead by then)

    // fused weight-cast + pad + bias-concat (one launch)
    prep<<<25736, 256, 0, stream>>>(Wk, Wq, Wv, Wr, W1, W2, bk, bq, bv,
                                    Wkqv_bf, Wr_bf, W1_bf, W2_bf, bkqv);

    hipFuncSetAttribute((const void*)gemm256<0>,
                        hipFuncAttributeMaxDynamicSharedMemorySize, 131072);
    hipFuncSetAttribute((const void*)gemm256<2>,
                        hipFuncAttributeMaxDynamicSharedMemorySize, 131072);
    hipFuncSetAttribute((const void*)gemm256<3>,
                        hipFuncAttributeMaxDynamicSharedMemorySize, 131072);

    // LN1: x -> Ybf, then transpose -> Xt [n*3136, 768]
    ln_f32<<<Nb * L, 192, 0, stream>>>(x, ln1_g, ln1_b, Ybf);
    transp_k<<<dim3(49, 12, 16), 256, 0, stream>>>(Ybf, Xt);

    // fused K/Q/V projection (N padded 1920->2048), split-store raw K/Q/V
    gemm256<0><<<dim3(8, 196), 512, 131072, stream>>>(
        Xt, Wkqv_bf, bkqv, nullptr, Kt, Qt, Vt, 50176, 2048, 768);

    // attention middle: exp-fused context + (normalize in att_k) + softmax-fused att
    hipMemsetAsync(ctx, 0, 4718592 + 49152, stream);
    context_k<<<dim3(7, 128), 256, 0, stream>>>(Kt, Vt, ctx, Sf);
    att_k<<<dim3(13, 128), 256, 0, stream>>>(ctx, Sf, Qt, attb);

    // Wr projection + residual (flat add, f32 x) -> x1 bf16
    gemm_nk<1><<<dim3(25, 6, 16), 256, 0, stream>>>(
        Wr_bf, attb, br, x, x1, 768, 3136, 384,
        (long)3200 * 384, (long)LD, (long)LD);

    // LN2: x1 -> Y2bf
    ln_bf<<<Nb * L, 192, 0, stream>>>(x1, ln2_g, ln2_b, Y2bf);

    // MLP1: [50176,3072] = Y2 @ W1^T, +b1, gelu, bf16
    gemm256<2><<<dim3(12, 196), 512, 131072, stream>>>(
        Y2bf, W1_bf, b1, nullptr, Hbf, nullptr, nullptr, 50176, 3072, 768);
    // MLP2: d_out(f32) = H @ W2^T + b2 + x1
    gemm256<3><<<dim3(3, 196), 512, 131072, stream>>>(
        Hbf, W2_bf, b2, x1, d_out, nullptr, nullptr, 50176, 768, 3072);
}